// Round 10
// baseline (55155.060 us; speedup 1.0000x reference)
//
#include <hip/hip_runtime.h>

#define TSTEPS 8192
#define HDIM   1024
#define NLAYER 4
#define NB     256          // 4 groups x 64 blocks, persistent, 1 block/CU
#define NT     512          // 8 waves/block
#define GB     64           // blocks per group (per layer)
#define EPB    16           // h elements per block (2 per wave)
#define RING   32           // ring depth (layer boundary), pairs

typedef float    f32x4 __attribute__((ext_vector_type(4)));
typedef unsigned u32x4 __attribute__((ext_vector_type(4)));
typedef unsigned long long u64;

struct GruParams {
  const float* xs;
  const float* Wih[NLAYER];
  const float* Whh[NLAYER];
  const float* bias[NLAYER];
  const float* bn[NLAYER];
  float* out;      // d_out (written by group 3)
  int*   tags;     // ws: NB produce-tags (readiness hints, validated by epochs)
  int*   ctags;    // ws: NB ring-consume tags (overwrite throttle)
  u64*   hbp;      // ws: NLAYER * 2 * HDIM (value,epoch) pairs
  u64*   ringp;    // ws: 3 * RING * HDIM (value,epoch) pairs
};

__device__ __forceinline__ float sigmoidf_(float x) {
  return 1.0f / (1.0f + __expf(-x));
}
__device__ __forceinline__ float tanhf_(float x) {
  const float e = __expf(2.0f * x);
  return 1.0f - 2.0f / (e + 1.0f);
}
__device__ __forceinline__ float rfl_(float x) {
  return __int_as_float(__builtin_amdgcn_readfirstlane(__float_as_int(x)));
}

// Cheap readiness sweep: 64 tags = 2 cache lines, one dword per lane.
// selflane >= 0 exempts this block's own tag (it is "done" by definition,
// and waiting for our own store's IF round-trip would serialize).
__device__ __forceinline__ void sweep_tags_(const int* tp, int bound,
                                            int selflane) {
  const int lane = (int)(threadIdx.x & 63);
  for (;;) {
    const int v = __hip_atomic_load(tp, __ATOMIC_RELAXED,
                                    __HIP_MEMORY_SCOPE_AGENT);
    const bool ok = (v >= bound) | (lane == selflane);
    if (__all(ok)) break;
    __builtin_amdgcn_s_sleep(1);
  }
}

// Validated gather of one 1024-element row of (value,epoch) pairs (this
// lane's 16) -> lds[0..1023]. Retries until every epoch == e; after the tag
// sweep this passes first try almost always. 8B pair stores are atomic, so
// a stale epoch simply means "retry" — no tearing.
__device__ __forceinline__ void poll_stage_row_(const u64* buf, unsigned e,
                                                float* lds, int lane) {
  const u64* p0 = buf + lane * 4;
  u32x4 r0, r1, r2, r3, r4, r5, r6, r7;
  for (;;) {
    asm volatile(
        "global_load_dwordx4 %0, %8, off sc1\n\t"
        "global_load_dwordx4 %1, %9, off sc1\n\t"
        "global_load_dwordx4 %2, %10, off sc1\n\t"
        "global_load_dwordx4 %3, %11, off sc1\n\t"
        "global_load_dwordx4 %4, %12, off sc1\n\t"
        "global_load_dwordx4 %5, %13, off sc1\n\t"
        "global_load_dwordx4 %6, %14, off sc1\n\t"
        "global_load_dwordx4 %7, %15, off sc1\n\t"
        "s_waitcnt vmcnt(0)"
        : "=&v"(r0), "=&v"(r1), "=&v"(r2), "=&v"(r3),
          "=&v"(r4), "=&v"(r5), "=&v"(r6), "=&v"(r7)
        : "v"(p0), "v"(p0 + 2), "v"(p0 + 256), "v"(p0 + 258),
          "v"(p0 + 512), "v"(p0 + 514), "v"(p0 + 768), "v"(p0 + 770)
        : "memory");
    bool ok = (r0.y == e) & (r0.w == e) & (r1.y == e) & (r1.w == e) &
              (r2.y == e) & (r2.w == e) & (r3.y == e) & (r3.w == e) &
              (r4.y == e) & (r4.w == e) & (r5.y == e) & (r5.w == e) &
              (r6.y == e) & (r6.w == e) & (r7.y == e) & (r7.w == e);
    if (__all(ok)) break;
    __builtin_amdgcn_s_sleep(1);
  }
  f32x4 v;
  v.x = __uint_as_float(r0.x); v.y = __uint_as_float(r0.z);
  v.z = __uint_as_float(r1.x); v.w = __uint_as_float(r1.z);
  *reinterpret_cast<f32x4*>(&lds[0 * 256 + lane * 4]) = v;
  v.x = __uint_as_float(r2.x); v.y = __uint_as_float(r2.z);
  v.z = __uint_as_float(r3.x); v.w = __uint_as_float(r3.z);
  *reinterpret_cast<f32x4*>(&lds[1 * 256 + lane * 4]) = v;
  v.x = __uint_as_float(r4.x); v.y = __uint_as_float(r4.z);
  v.z = __uint_as_float(r5.x); v.w = __uint_as_float(r5.z);
  *reinterpret_cast<f32x4*>(&lds[2 * 256 + lane * 4]) = v;
  v.x = __uint_as_float(r6.x); v.y = __uint_as_float(r6.z);
  v.z = __uint_as_float(r7.x); v.w = __uint_as_float(r7.z);
  *reinterpret_cast<f32x4*>(&lds[3 * 256 + lane * 4]) = v;
}

__device__ __forceinline__ void stage_plain_row_(const float* row, float* lds,
                                                 int lane) {
#pragma unroll
  for (int i = 0; i < 4; ++i)
    *reinterpret_cast<f32x4*>(&lds[i * 256 + lane * 4]) =
        *reinterpret_cast<const f32x4*>(row + i * 256 + lane * 4);
}

// Layer-pipelined persistent GRU (R8 structure) with two-phase sync:
// cheap per-block tag sweep (2 lines) -> single validated 8KB gather.
// Cuts poll-retry bandwidth ~30x vs polling the data row directly.
__global__ __attribute__((amdgpu_flat_work_group_size(NT, NT),
                          amdgpu_waves_per_eu(2, 2)))
void gru_pipe(GruParams p) {
  __shared__ float xst[2][HDIM];
  __shared__ float hst[2][HDIM];
  __shared__ int hflag[2];
  const int tid  = threadIdx.x;
  const int lane = tid & 63;
  const int wave = tid >> 6;
  const int blk  = blockIdx.x;
  const int g    = blk >> 6;
  const int m    = blk & 63;
  const int j0   = m * EPB + wave * 2;

  // ---- weights: 12 rows (2 elems x (3 ih + 3 hh)) -> 48 f32x4 on-chip ----
  const float* Wih = p.Wih[g];
  const float* Whh = p.Whh[g];
  f32x4 w4[48];
#pragma unroll
  for (int e = 0; e < 2; ++e) {
#pragma unroll
    for (int dd = 0; dd < 6; ++dd) {
      const float* W = (dd < 3) ? Wih : Whh;
      const int gate = (dd < 3) ? dd : dd - 3;
      const float* src = W + ((size_t)gate * HDIM + (j0 + e)) * HDIM + lane * 4;
#pragma unroll
      for (int i = 0; i < 4; ++i)
        w4[(e * 6 + dd) * 4 + i] = *reinterpret_cast<const f32x4*>(src + i * 256);
    }
  }
  const float bA0 = rfl_(p.bias[g][j0]);
  const float bA1 = rfl_(p.bias[g][HDIM + j0]);
  const float bA2 = rfl_(p.bias[g][2 * HDIM + j0]);
  const float bnA = rfl_(p.bn[g][j0]);
  const float bB0 = rfl_(p.bias[g][j0 + 1]);
  const float bB1 = rfl_(p.bias[g][HDIM + j0 + 1]);
  const float bB2 = rfl_(p.bias[g][2 * HDIM + j0 + 1]);
  const float bnB = rfl_(p.bn[g][j0 + 1]);
  float hregA = 0.f, hregB = 0.f;

  u64* hp = p.hbp + (size_t)g * 2 * HDIM;
  const u64* ring_in  = p.ringp + (size_t)(g - 1) * RING * HDIM;  // g>0
  u64*       ring_out = p.ringp + (size_t)g * RING * HDIM;        // g<3
  const int* owntp = p.tags + g * GB + lane;
  const int* uptp  = (g > 0) ? (p.tags + (g - 1) * GB + lane) : owntp;
  const int* dwnp  = (g < 3) ? (p.ctags + (g + 1) * GB + lane) : owntp;

  // ---- prologue: flags, stage x(0) ----
  if (tid == 0) { hflag[0] = -1; hflag[1] = -1; }
  if (wave == 1) {
    if (g == 0)
      stage_plain_row_(p.xs, &xst[0][0], lane);
    else {
      sweep_tags_(uptp, 1, -1);
      poll_stage_row_(ring_in, 1u, &xst[0][0], lane);
      if (lane == 0)
        __hip_atomic_store(&p.ctags[blk], 1, __ATOMIC_RELAXED,
                           __HIP_MEMORY_SCOPE_AGENT);
    }
  }
  __syncthreads();

  for (int t = 0; t < TSTEPS; ++t) {
    const int par = t & 1;

    // ---- top-of-tick produce-tag: barrier (end of t-1) guarantees all 8
    //      waves issued their epoch-t pair stores; consumers validate anyway.
    if (tid == 0 && t > 0)
      __hip_atomic_store(&p.tags[blk], t, __ATOMIC_RELAXED,
                         __HIP_MEMORY_SCOPE_AGENT);

    // ---- ih FMAs from xst[par] (h-independent; overlaps the h RT) ----
    float A_ir = 0.f, A_iz = 0.f, A_in = 0.f;
    float B_ir = 0.f, B_iz = 0.f, B_in = 0.f;
#pragma unroll
    for (int i = 0; i < 4; ++i) {
      const f32x4 v = *reinterpret_cast<const f32x4*>(&xst[par][i * 256 + lane * 4]);
#pragma unroll
      for (int q = 0; q < 4; ++q) {
        const float xq = v[q];
        A_ir = fmaf(w4[ 0 + i][q], xq, A_ir);
        A_iz = fmaf(w4[ 4 + i][q], xq, A_iz);
        A_in = fmaf(w4[ 8 + i][q], xq, A_in);
        B_ir = fmaf(w4[24 + i][q], xq, B_ir);
        B_iz = fmaf(w4[28 + i][q], xq, B_iz);
        B_in = fmaf(w4[32 + i][q], xq, B_in);
      }
    }

    // ---- wave role tasks ----
    if (wave == 0) {
      if (t > 0) {
        sweep_tags_(owntp, t, m);                       // cheap detect
        poll_stage_row_(hp + (size_t)par * HDIM, (unsigned)t,
                        &hst[par][0], lane);            // one validated RT
        asm volatile("s_waitcnt lgkmcnt(0)" ::: "memory");
        if (lane == 0) ((volatile int*)hflag)[par] = t;
      }
    } else if (wave == 1) {
      // x(t+1) staging: hides under the h round-trip (R8 placement)
      if (t + 1 < TSTEPS) {
        const int pn = (t + 1) & 1;
        if (g == 0)
          stage_plain_row_(p.xs + (size_t)(t + 1) * HDIM, &xst[pn][0], lane);
        else {
          sweep_tags_(uptp, t + 2, -1);
          poll_stage_row_(ring_in + (size_t)((t + 1) & (RING - 1)) * HDIM,
                          (unsigned)(t + 2), &xst[pn][0], lane);
          if (lane == 0)
            __hip_atomic_store(&p.ctags[blk], t + 2, __ATOMIC_RELAXED,
                               __HIP_MEMORY_SCOPE_AGENT);
        }
      }
    } else if (wave == 2) {
      // ring-overwrite throttle: every 16 ticks, bound t-14 keeps the next
      // 16 writes safe (slot t&31 previously held epoch t-31, consumed at
      // ctag >= t-30; t-14 > t'-30 for all t' in [t, t+16)).
      if (g < 3 && t >= 32 && (t & 15) == 0) {
        const int bound = t - 14;
        const int* tp = dwnp;
        for (;;) {
          const int v = __hip_atomic_load(tp, __ATOMIC_RELAXED,
                                          __HIP_MEMORY_SCOPE_AGENT);
          if (__all(v >= bound)) break;
          __builtin_amdgcn_s_sleep(4);
        }
      }
    }

    // ---- wait h ready (LDS flag, no IF traffic); hh FMAs ----
    float A_hr = 0.f, A_hz = 0.f, A_hn = 0.f;
    float B_hr = 0.f, B_hz = 0.f, B_hn = 0.f;
    if (t > 0) {
      if (wave != 0) {
        while (((volatile int*)hflag)[par] != t) { }
        asm volatile("s_waitcnt lgkmcnt(0)" ::: "memory");
        __builtin_amdgcn_sched_barrier(0);
      }
#pragma unroll
      for (int i = 0; i < 4; ++i) {
        const f32x4 v = *reinterpret_cast<const f32x4*>(&hst[par][i * 256 + lane * 4]);
#pragma unroll
        for (int q = 0; q < 4; ++q) {
          const float hq = v[q];
          A_hr = fmaf(w4[12 + i][q], hq, A_hr);
          A_hz = fmaf(w4[16 + i][q], hq, A_hz);
          A_hn = fmaf(w4[20 + i][q], hq, A_hn);
          B_hr = fmaf(w4[36 + i][q], hq, B_hr);
          B_hz = fmaf(w4[40 + i][q], hq, B_hz);
          B_hn = fmaf(w4[44 + i][q], hq, B_hn);
        }
      }
    }

    // ---- reduce (r,z pre-added) + gates ----
    float sAr = A_ir + A_hr, sAz = A_iz + A_hz;
    float sBr = B_ir + B_hr, sBz = B_iz + B_hz;
#pragma unroll
    for (int off = 32; off > 0; off >>= 1) {
      sAr  += __shfl_xor(sAr,  off, 64);
      sAz  += __shfl_xor(sAz,  off, 64);
      A_in += __shfl_xor(A_in, off, 64);
      A_hn += __shfl_xor(A_hn, off, 64);
      sBr  += __shfl_xor(sBr,  off, 64);
      sBz  += __shfl_xor(sBz,  off, 64);
      B_in += __shfl_xor(B_in, off, 64);
      B_hn += __shfl_xor(B_hn, off, 64);
    }
    const float rA = sigmoidf_(sAr + bA0);
    const float zA = sigmoidf_(sAz + bA1);
    const float nA = tanhf_(A_in + bA2 + rA * (A_hn + bnA));
    const float hA = nA + zA * (hregA - nA);
    const float rB = sigmoidf_(sBr + bB0);
    const float zB = sigmoidf_(sBz + bB1);
    const float nB = tanhf_(B_in + bB2 + rB * (B_hn + bnB));
    const float hB = nB + zB * (hregB - nB);
    hregA = hA; hregB = hB;

    // ---- publish: epoch-carrying pair stores, fire-and-forget ----
    if (lane == 0) {
      u32x4 pk;
      pk.x = __float_as_uint(hA); pk.y = (unsigned)(t + 1);
      pk.z = __float_as_uint(hB); pk.w = (unsigned)(t + 1);
      u64* hdst = hp + (size_t)((t + 1) & 1) * HDIM + j0;
      asm volatile("global_store_dwordx4 %0, %1, off sc1"
                   :: "v"(hdst), "v"(pk) : "memory");
      if (g < 3) {
        u64* rdst = ring_out + (size_t)(t & (RING - 1)) * HDIM + j0;
        asm volatile("global_store_dwordx4 %0, %1, off sc1"
                     :: "v"(rdst), "v"(pk) : "memory");
      } else {
        const u64 po = ((u64)__float_as_uint(hB) << 32) |
                       (u64)__float_as_uint(hA);
        float* od = p.out + (size_t)t * HDIM + j0;
        asm volatile("global_store_dwordx2 %0, %1, off sc1"
                     :: "v"(od), "v"(po) : "memory");
      }
    }
    // one barrier/tick: protects xst/hst parity buffers + hflag reuse,
    // and guarantees all pair stores are issued before next tick's tag.
    __syncthreads();
  }

  // epilogue tag: downstream sweeps need tags up to TSTEPS (x staging at
  // tick TSTEPS-2 waits for uptag >= TSTEPS) — without this they deadlock.
  if (tid == 0)
    __hip_atomic_store(&p.tags[blk], TSTEPS, __ATOMIC_RELAXED,
                       __HIP_MEMORY_SCOPE_AGENT);
}

extern "C" void kernel_launch(void* const* d_in, const int* in_sizes, int n_in,
                              void* d_out, int out_size, void* d_ws, size_t ws_size,
                              hipStream_t stream) {
  GruParams p;
  p.xs = (const float*)d_in[0];
  for (int l = 0; l < NLAYER; ++l) {
    p.Wih[l]  = (const float*)d_in[1 + 4 * l];
    p.Whh[l]  = (const float*)d_in[2 + 4 * l];
    p.bias[l] = (const float*)d_in[3 + 4 * l];
    p.bn[l]   = (const float*)d_in[4 + 4 * l];
  }
  char* ws = (char*)d_ws;
  size_t off = 0;
  p.tags = (int*)(ws + off);
  off += (size_t)NB * sizeof(int);
  p.ctags = (int*)(ws + off);
  off += (size_t)NB * sizeof(int);
  off = (off + 255) & ~(size_t)255;
  p.hbp = (u64*)(ws + off);
  const size_t hbp_bytes = (size_t)NLAYER * 2 * HDIM * sizeof(u64);
  off += hbp_bytes;
  p.ringp = (u64*)(ws + off);
  const size_t ring_bytes = (size_t)3 * RING * HDIM * sizeof(u64);
  off += ring_bytes;
  p.out = (float*)d_out;

  // Replay safety: tags/epochs restart each launch; clear all sync state.
  (void)hipMemsetAsync(p.tags, 0, (size_t)2 * NB * sizeof(int), stream);
  (void)hipMemsetAsync(p.hbp, 0, hbp_bytes, stream);
  (void)hipMemsetAsync(p.ringp, 0, ring_bytes, stream);
  gru_pipe<<<dim3(NB), dim3(NT), 0, stream>>>(p);
}

// Round 11
// 38059.543 us; speedup vs baseline: 1.4492x; 1.4492x over previous
//
#include <hip/hip_runtime.h>

#define TSTEPS 8192
#define HDIM   1024
#define NLAYER 4
#define NB     256          // 4 groups x 64 blocks, persistent, 1 block/CU
#define NT     512          // 8 waves/block
#define GB     64           // blocks per group (per layer)
#define EPB    16           // h elements per block (2 per wave)
#define RING   16           // ring depth (layer boundary), pair rows
#define NREP   8            // replication factor for h/ring pair rows

typedef float    f32x4 __attribute__((ext_vector_type(4)));
typedef unsigned u32x4 __attribute__((ext_vector_type(4)));
typedef unsigned long long u64;

struct GruParams {
  const float* xs;
  const float* Wih[NLAYER];
  const float* Whh[NLAYER];
  const float* bias[NLAYER];
  const float* bn[NLAYER];
  float* out;      // d_out (written by group 3)
  int*   ctags;    // ws: NB ring-consume tags (overwrite throttle)
  u64*   hbp;      // ws: NLAYER * 2 * NREP * HDIM (value,epoch) pairs
  u64*   ringp;    // ws: 3 * RING * NREP * HDIM (value,epoch) pairs
};

__device__ __forceinline__ float sigmoidf_(float x) {
  return 1.0f / (1.0f + __expf(-x));
}
__device__ __forceinline__ float tanhf_(float x) {
  const float e = __expf(2.0f * x);
  return 1.0f - 2.0f / (e + 1.0f);
}
__device__ __forceinline__ float rfl_(float x) {
  return __int_as_float(__builtin_amdgcn_readfirstlane(__float_as_int(x)));
}

// Poll-gather one 1024-element row of (value,epoch) pairs (this lane's 16)
// until every epoch == e, then stage values into lds[0..1023]. The gather IS
// the readiness check: one coherence-point round-trip, no tags, no ack.
// Caller passes a per-consumer REPLICA base, so at most NB/NREP blocks read
// any given line concurrently (avoids same-line fan-in serialization).
__device__ __forceinline__ void poll_stage_row_(const u64* buf, unsigned e,
                                                float* lds, int lane) {
  const u64* p0 = buf + lane * 4;
  u32x4 r0, r1, r2, r3, r4, r5, r6, r7;
  for (;;) {
    asm volatile(
        "global_load_dwordx4 %0, %8, off sc1\n\t"
        "global_load_dwordx4 %1, %9, off sc1\n\t"
        "global_load_dwordx4 %2, %10, off sc1\n\t"
        "global_load_dwordx4 %3, %11, off sc1\n\t"
        "global_load_dwordx4 %4, %12, off sc1\n\t"
        "global_load_dwordx4 %5, %13, off sc1\n\t"
        "global_load_dwordx4 %6, %14, off sc1\n\t"
        "global_load_dwordx4 %7, %15, off sc1\n\t"
        "s_waitcnt vmcnt(0)"
        : "=&v"(r0), "=&v"(r1), "=&v"(r2), "=&v"(r3),
          "=&v"(r4), "=&v"(r5), "=&v"(r6), "=&v"(r7)
        : "v"(p0), "v"(p0 + 2), "v"(p0 + 256), "v"(p0 + 258),
          "v"(p0 + 512), "v"(p0 + 514), "v"(p0 + 768), "v"(p0 + 770)
        : "memory");
    bool ok = (r0.y == e) & (r0.w == e) & (r1.y == e) & (r1.w == e) &
              (r2.y == e) & (r2.w == e) & (r3.y == e) & (r3.w == e) &
              (r4.y == e) & (r4.w == e) & (r5.y == e) & (r5.w == e) &
              (r6.y == e) & (r6.w == e) & (r7.y == e) & (r7.w == e);
    if (__all(ok)) break;
    __builtin_amdgcn_s_sleep(1);
  }
  f32x4 v;
  v.x = __uint_as_float(r0.x); v.y = __uint_as_float(r0.z);
  v.z = __uint_as_float(r1.x); v.w = __uint_as_float(r1.z);
  *reinterpret_cast<f32x4*>(&lds[0 * 256 + lane * 4]) = v;
  v.x = __uint_as_float(r2.x); v.y = __uint_as_float(r2.z);
  v.z = __uint_as_float(r3.x); v.w = __uint_as_float(r3.z);
  *reinterpret_cast<f32x4*>(&lds[1 * 256 + lane * 4]) = v;
  v.x = __uint_as_float(r4.x); v.y = __uint_as_float(r4.z);
  v.z = __uint_as_float(r5.x); v.w = __uint_as_float(r5.z);
  *reinterpret_cast<f32x4*>(&lds[2 * 256 + lane * 4]) = v;
  v.x = __uint_as_float(r6.x); v.y = __uint_as_float(r6.z);
  v.z = __uint_as_float(r7.x); v.w = __uint_as_float(r7.z);
  *reinterpret_cast<f32x4*>(&lds[3 * 256 + lane * 4]) = v;
}

__device__ __forceinline__ void stage_plain_row_(const float* row, float* lds,
                                                 int lane) {
#pragma unroll
  for (int i = 0; i < 4; ++i)
    *reinterpret_cast<f32x4*>(&lds[i * 256 + lane * 4]) =
        *reinterpret_cast<const f32x4*>(row + i * 256 + lane * 4);
}

// Layer-pipelined persistent GRU (R8 structure), with NREP-replicated h and
// ring pair-rows to break coherence-point same-line read serialization, and
// wave0's h-poll hoisted to the top of the tick (off the ih-FMA shadow).
__global__ __attribute__((amdgpu_flat_work_group_size(NT, NT),
                          amdgpu_waves_per_eu(2, 2)))
void gru_pipe(GruParams p) {
  __shared__ float xst[2][HDIM];
  __shared__ float hst[2][HDIM];
  __shared__ int hflag[2];
  const int tid  = threadIdx.x;
  const int lane = tid & 63;
  const int wave = tid >> 6;
  const int blk  = blockIdx.x;
  const int g    = blk >> 6;
  const int m    = blk & 63;
  const int rep  = m & (NREP - 1);      // this block's read replica
  const int j0   = m * EPB + wave * 2;

  // ---- weights: 12 rows (2 elems x (3 ih + 3 hh)) -> 48 f32x4 on-chip ----
  const float* Wih = p.Wih[g];
  const float* Whh = p.Whh[g];
  f32x4 w4[48];
#pragma unroll
  for (int e = 0; e < 2; ++e) {
#pragma unroll
    for (int dd = 0; dd < 6; ++dd) {
      const float* W = (dd < 3) ? Wih : Whh;
      const int gate = (dd < 3) ? dd : dd - 3;
      const float* src = W + ((size_t)gate * HDIM + (j0 + e)) * HDIM + lane * 4;
#pragma unroll
      for (int i = 0; i < 4; ++i)
        w4[(e * 6 + dd) * 4 + i] = *reinterpret_cast<const f32x4*>(src + i * 256);
    }
  }
  const float bA0 = rfl_(p.bias[g][j0]);
  const float bA1 = rfl_(p.bias[g][HDIM + j0]);
  const float bA2 = rfl_(p.bias[g][2 * HDIM + j0]);
  const float bnA = rfl_(p.bn[g][j0]);
  const float bB0 = rfl_(p.bias[g][j0 + 1]);
  const float bB1 = rfl_(p.bias[g][HDIM + j0 + 1]);
  const float bB2 = rfl_(p.bias[g][2 * HDIM + j0 + 1]);
  const float bnB = rfl_(p.bn[g][j0 + 1]);
  float hregA = 0.f, hregB = 0.f;

  // h layout: [g][par][rep][HDIM pairs]; ring: [bnd][slot][rep][HDIM pairs]
  u64* hp = p.hbp + (size_t)g * 2 * NREP * HDIM;
  const u64* ring_in  = p.ringp + (size_t)(g - 1) * RING * NREP * HDIM; // g>0
  u64*       ring_out = p.ringp + (size_t)g * RING * NREP * HDIM;       // g<3
  const int* dwnp = (g < 3) ? (p.ctags + (g + 1) * GB + lane)
                            : (p.ctags + g * GB + lane);

  // ---- prologue: flags, stage x(0) ----
  if (tid == 0) { hflag[0] = -1; hflag[1] = -1; }
  if (wave == 1) {
    if (g == 0)
      stage_plain_row_(p.xs, &xst[0][0], lane);
    else {
      poll_stage_row_(ring_in + (size_t)rep * HDIM, 1u, &xst[0][0], lane);
      if (lane == 0)
        __hip_atomic_store(&p.ctags[blk], 1, __ATOMIC_RELAXED,
                           __HIP_MEMORY_SCOPE_AGENT);
    }
  }
  __syncthreads();

  for (int t = 0; t < TSTEPS; ++t) {
    const int par = t & 1;

    // ---- wave0 FIRST: poll+stage h(t) (critical path head) ----
    if (wave == 0) {
      if (t > 0) {
        poll_stage_row_(hp + ((size_t)par * NREP + rep) * HDIM, (unsigned)t,
                        &hst[par][0], lane);
        asm volatile("s_waitcnt lgkmcnt(0)" ::: "memory");
        if (lane == 0) ((volatile int*)hflag)[par] = t;
      }
    }

    // ---- ih FMAs from xst[par] (h-independent; overlaps the h RT) ----
    float A_ir = 0.f, A_iz = 0.f, A_in = 0.f;
    float B_ir = 0.f, B_iz = 0.f, B_in = 0.f;
#pragma unroll
    for (int i = 0; i < 4; ++i) {
      const f32x4 v = *reinterpret_cast<const f32x4*>(&xst[par][i * 256 + lane * 4]);
#pragma unroll
      for (int q = 0; q < 4; ++q) {
        const float xq = v[q];
        A_ir = fmaf(w4[ 0 + i][q], xq, A_ir);
        A_iz = fmaf(w4[ 4 + i][q], xq, A_iz);
        A_in = fmaf(w4[ 8 + i][q], xq, A_in);
        B_ir = fmaf(w4[24 + i][q], xq, B_ir);
        B_iz = fmaf(w4[28 + i][q], xq, B_iz);
        B_in = fmaf(w4[32 + i][q], xq, B_in);
      }
    }

    // ---- other wave role tasks (all hidden under the h round-trip) ----
    if (wave == 1) {
      // x(t+1) staging into the other parity buffer
      if (t + 1 < TSTEPS) {
        const int pn = (t + 1) & 1;
        if (g == 0)
          stage_plain_row_(p.xs + (size_t)(t + 1) * HDIM, &xst[pn][0], lane);
        else {
          poll_stage_row_(ring_in +
                              ((size_t)((t + 1) & (RING - 1)) * NREP + rep) * HDIM,
                          (unsigned)(t + 2), &xst[pn][0], lane);
          if (lane == 0)
            __hip_atomic_store(&p.ctags[blk], t + 2, __ATOMIC_RELAXED,
                               __HIP_MEMORY_SCOPE_AGENT);
        }
      }
    } else if (wave == 2) {
      // ring-overwrite throttle: every 4 ticks, bound t-10.
      // Overwrite of slot t&15 at tick t needs downstream ctag >= t-14;
      // worst in-window tick t0+3 needs >= t0-11; bound t0-10 guarantees it.
      if (g < 3 && t >= 16 && (t & 3) == 0) {
        const int bound = t - 10;
        for (;;) {
          const int v = __hip_atomic_load(dwnp, __ATOMIC_RELAXED,
                                          __HIP_MEMORY_SCOPE_AGENT);
          if (__all(v >= bound)) break;
          __builtin_amdgcn_s_sleep(4);
        }
      }
    }

    // ---- wait h ready (LDS flag, no fabric traffic); hh FMAs ----
    float A_hr = 0.f, A_hz = 0.f, A_hn = 0.f;
    float B_hr = 0.f, B_hz = 0.f, B_hn = 0.f;
    if (t > 0) {
      if (wave != 0) {
        while (((volatile int*)hflag)[par] != t) { }
        asm volatile("s_waitcnt lgkmcnt(0)" ::: "memory");
        __builtin_amdgcn_sched_barrier(0);
      }
#pragma unroll
      for (int i = 0; i < 4; ++i) {
        const f32x4 v = *reinterpret_cast<const f32x4*>(&hst[par][i * 256 + lane * 4]);
#pragma unroll
        for (int q = 0; q < 4; ++q) {
          const float hq = v[q];
          A_hr = fmaf(w4[12 + i][q], hq, A_hr);
          A_hz = fmaf(w4[16 + i][q], hq, A_hz);
          A_hn = fmaf(w4[20 + i][q], hq, A_hn);
          B_hr = fmaf(w4[36 + i][q], hq, B_hr);
          B_hz = fmaf(w4[40 + i][q], hq, B_hz);
          B_hn = fmaf(w4[44 + i][q], hq, B_hn);
        }
      }
    }

    // ---- reduce (r,z pre-added) + gates ----
    float sAr = A_ir + A_hr, sAz = A_iz + A_hz;
    float sBr = B_ir + B_hr, sBz = B_iz + B_hz;
#pragma unroll
    for (int off = 32; off > 0; off >>= 1) {
      sAr  += __shfl_xor(sAr,  off, 64);
      sAz  += __shfl_xor(sAz,  off, 64);
      A_in += __shfl_xor(A_in, off, 64);
      A_hn += __shfl_xor(A_hn, off, 64);
      sBr  += __shfl_xor(sBr,  off, 64);
      sBz  += __shfl_xor(sBz,  off, 64);
      B_in += __shfl_xor(B_in, off, 64);
      B_hn += __shfl_xor(B_hn, off, 64);
    }
    const float rA = sigmoidf_(sAr + bA0);
    const float zA = sigmoidf_(sAz + bA1);
    const float nA = tanhf_(A_in + bA2 + rA * (A_hn + bnA));
    const float hA = nA + zA * (hregA - nA);
    const float rB = sigmoidf_(sBr + bB0);
    const float zB = sigmoidf_(sBz + bB1);
    const float nB = tanhf_(B_in + bB2 + rB * (B_hn + bnB));
    const float hB = nB + zB * (hregB - nB);
    hregA = hA; hregB = hB;

    // ---- publish: epoch-carrying pair stores to ALL replicas ----
    if (lane == 0) {
      u32x4 pk;
      pk.x = __float_as_uint(hA); pk.y = (unsigned)(t + 1);
      pk.z = __float_as_uint(hB); pk.w = (unsigned)(t + 1);
      u64* hbase = hp + (size_t)((t + 1) & 1) * NREP * HDIM + j0;
#pragma unroll
      for (int r2 = 0; r2 < NREP; ++r2)
        asm volatile("global_store_dwordx4 %0, %1, off sc1"
                     :: "v"(hbase + (size_t)r2 * HDIM), "v"(pk) : "memory");
      if (g < 3) {
        u64* rbase = ring_out + (size_t)(t & (RING - 1)) * NREP * HDIM + j0;
#pragma unroll
        for (int r2 = 0; r2 < NREP; ++r2)
          asm volatile("global_store_dwordx4 %0, %1, off sc1"
                       :: "v"(rbase + (size_t)r2 * HDIM), "v"(pk) : "memory");
      } else {
        const u64 po = ((u64)__float_as_uint(hB) << 32) |
                       (u64)__float_as_uint(hA);
        float* od = p.out + (size_t)t * HDIM + j0;
        asm volatile("global_store_dwordx2 %0, %1, off sc1"
                     :: "v"(od), "v"(po) : "memory");
      }
    }
    // one barrier/tick: protects xst/hst parity buffers + hflag reuse,
    // and guarantees all pair stores are issued before the next tick.
    __syncthreads();
  }
}

extern "C" void kernel_launch(void* const* d_in, const int* in_sizes, int n_in,
                              void* d_out, int out_size, void* d_ws, size_t ws_size,
                              hipStream_t stream) {
  GruParams p;
  p.xs = (const float*)d_in[0];
  for (int l = 0; l < NLAYER; ++l) {
    p.Wih[l]  = (const float*)d_in[1 + 4 * l];
    p.Whh[l]  = (const float*)d_in[2 + 4 * l];
    p.bias[l] = (const float*)d_in[3 + 4 * l];
    p.bn[l]   = (const float*)d_in[4 + 4 * l];
  }
  char* ws = (char*)d_ws;
  size_t off = 0;
  p.ctags = (int*)(ws + off);
  off += (size_t)NB * sizeof(int);
  off = (off + 255) & ~(size_t)255;
  p.hbp = (u64*)(ws + off);
  const size_t hbp_bytes = (size_t)NLAYER * 2 * NREP * HDIM * sizeof(u64);
  off += hbp_bytes;
  p.ringp = (u64*)(ws + off);
  const size_t ring_bytes = (size_t)3 * RING * NREP * HDIM * sizeof(u64);
  off += ring_bytes;
  p.out = (float*)d_out;

  // Replay safety: epochs restart at 1 each launch; clear all epoch state.
  (void)hipMemsetAsync(p.ctags, 0, (size_t)NB * sizeof(int), stream);
  (void)hipMemsetAsync(p.hbp, 0, hbp_bytes, stream);
  (void)hipMemsetAsync(p.ringp, 0, ring_bytes, stream);
  gru_pipe<<<dim3(NB), dim3(NT), 0, stream>>>(p);
}